// Round 1
// baseline (34.028 us; speedup 1.0000x reference)
//
#include <hip/hip_runtime.h>
#include <hip/hip_bf16.h>

// Problem constants (from reference): N=32, T=2048, C=512, V=500
#define RN 32
#define RT 2048
#define RC 512
#define RV 500

// float32(math.log(0.9))
#define LOG09 (-0.10536052f)

// Kernel 1: per-row keep-mask + stable exclusive scan -> inverse index map + lengths.
// grid = N blocks, block = 256 threads, 8 time-steps per thread.
__global__ void fr_mask_scan(const float* __restrict__ ctc,
                             const int* __restrict__ x_lens,
                             const int* __restrict__ blank_id_p,
                             int* __restrict__ src_idx,   // [N*T] in ws
                             int* __restrict__ lens_i,    // [N]   in ws
                             float* __restrict__ lens_f)  // [N]   tail of d_out
{
    const int n   = blockIdx.x;
    const int tid = threadIdx.x;           // 0..255
    const int blank = blank_id_p[0];
    const int xlen  = x_lens[n];

    const float* row = ctc + (size_t)n * RT * RV;
    const int base = tid * 8;

    unsigned flags = 0;
    int cnt = 0;
#pragma unroll
    for (int j = 0; j < 8; ++j) {
        const int t = base + j;
        const bool keep = (t < xlen) && (row[(size_t)t * RV + blank] < LOG09);
        flags |= (keep ? 1u : 0u) << j;
        cnt += keep ? 1 : 0;
    }

    __shared__ int s[256];
    s[tid] = cnt;
    __syncthreads();
    // Hillis-Steele inclusive scan over 256 thread-counts (8 steps).
#pragma unroll
    for (int off = 1; off < 256; off <<= 1) {
        int v = 0;
        if (tid >= off) v = s[tid - off];
        __syncthreads();
        if (tid >= off) s[tid] += v;
        __syncthreads();
    }
    const int excl  = s[tid] - cnt;
    const int total = s[255];

    int* srow = src_idx + n * RT;
    int pos = excl;
#pragma unroll
    for (int j = 0; j < 8; ++j) {
        if ((flags >> j) & 1u) {
            srow[pos++] = base + j;
        }
    }

    if (tid == 0) {
        lens_i[n] = total;
        lens_f[n] = (float)total;   // harness reads the concatenated output as f32
    }
}

// Kernel 2: gather/zero-fill every output row.
// Each block (256 thr) writes 2 output rows; each row = 512 floats = 128 float4.
__global__ void fr_gather(const float* __restrict__ x,
                          const int* __restrict__ src_idx,
                          const int* __restrict__ lens_i,
                          float4* __restrict__ out)
{
    const int r    = blockIdx.x * 2 + (threadIdx.x >> 7);  // global output row in [0, N*T)
    const int lane = threadIdx.x & 127;
    const int n = r >> 11;        // / T (T = 2048)
    const int p = r & (RT - 1);   // % T

    float4 v = make_float4(0.f, 0.f, 0.f, 0.f);
    if (p < lens_i[n]) {
        const int t = src_idx[n * RT + p];
        const float4* xr = (const float4*)(x + ((size_t)n * RT + t) * RC);
        v = xr[lane];
    }
    out[(size_t)r * (RC / 4) + lane] = v;
}

extern "C" void kernel_launch(void* const* d_in, const int* in_sizes, int n_in,
                              void* d_out, int out_size, void* d_ws, size_t ws_size,
                              hipStream_t stream) {
    const float* x        = (const float*)d_in[0];   // [N, T, C] f32
    const int*   x_lens   = (const int*)d_in[1];     // [N] int32 (jax x64-off demotes int64)
    const float* ctc      = (const float*)d_in[2];   // [N, T, V] f32
    const int*   blank_id = (const int*)d_in[3];     // scalar

    float* out    = (float*)d_out;                   // [N*T*C] + [N] lens (as f32)
    float* lens_f = out + (size_t)RN * RT * RC;

    int* src_idx = (int*)d_ws;                       // [N*T]
    int* lens_i  = src_idx + RN * RT;                // [N]

    fr_mask_scan<<<RN, 256, 0, stream>>>(ctc, x_lens, blank_id, src_idx, lens_i, lens_f);
    fr_gather<<<(RN * RT) / 2, 256, 0, stream>>>(x, src_idx, lens_i, (float4*)out);
}